// Round 8
// baseline (115.769 us; speedup 1.0000x reference)
//
#include <hip/hip_runtime.h>
#include <math.h>

#define NN 100000
#define NE 500000

typedef short bf16x8 __attribute__((ext_vector_type(8)));
typedef float f32x4  __attribute__((ext_vector_type(4)));

static __device__ __forceinline__ unsigned short f2bf_rne(float x) {
    unsigned int u = __builtin_bit_cast(unsigned int, x);
    unsigned int r = u + 0x7fffu + ((u >> 16) & 1u);
    return (unsigned short)(r >> 16);
}
static __device__ __forceinline__ float bf2f(unsigned short b) {
    return __builtin_bit_cast(float, (unsigned int)b << 16);
}

// ---------------------------------------------------------------------------
// Kernel 0: pack merged weight Wc (128x128) into MFMA B-fragment order,
// split hi/lo bf16.  Wc[k][j] = (j<64) ? W1[k][j] : W1[128+k][j-64].
// Frag element (jt,kt,lane l,e):  k = kt*32 + (l>>4)*8 + e,  j = jt*16 + (l&15)
// stored at WP[((jt*4+kt)*64 + l)*8 + e]  -> one 16B bf16x8 per lane.
// ---------------------------------------------------------------------------
__global__ __launch_bounds__(256)
void prepack_w(const float* __restrict__ W1, unsigned short* __restrict__ WPh,
               unsigned short* __restrict__ WPl)
{
    int idx = blockIdx.x * 256 + threadIdx.x;   // 0..16383
    int e  = idx & 7;
    int l  = (idx >> 3) & 63;
    int kt = (idx >> 9) & 3;
    int jt = idx >> 11;
    int k = kt * 32 + (l >> 4) * 8 + e;
    int j = jt * 16 + (l & 15);
    float w = (j < 64) ? W1[k * 64 + j] : W1[(128 + k) * 64 + (j - 64)];
    unsigned short hb = f2bf_rne(w);
    unsigned short lb = f2bf_rne(w - bf2f(hb));
    WPh[idx] = hb;
    WPl[idx] = lb;
}

// ---------------------------------------------------------------------------
// Kernel 1: per-node projection via MFMA (mixed precision).
//   AB[n][0:64]   = h[n] @ W1[0:128,:]  + b1   (b1 folded)
//   AB[n][64:128] = h[n] @ W1[128:256,:]
// A = h rows (truncated bf16), B = Wc split hi+lo -> 2 MFMAs per tile:
//   acc += A*Wh ; acc += A*Wl     (error ~1.6e-3 std on logits; boundary
//   decisions are recomputed in fp32 in edge_sample, margin 0.02)
// Wave = 16 node rows; block = 4 waves = 64 rows. K=128 -> 4 k-steps.
// 8 j-tiles of 16. No LDS. 64 MFMAs/wave.
// Layouts (16x16x32 bf16): A lane l: row=l&15, k=8*(l>>4)+e (contig-8);
// B lane l: col=l&15, same k; D lane l: col=l&15, row=4*(l>>4)+r (m89).
// ---------------------------------------------------------------------------
__global__ __launch_bounds__(256)
void mfma_proj(const float* __restrict__ h, const unsigned short* __restrict__ WPh,
               const unsigned short* __restrict__ WPl, const float* __restrict__ b1,
               float* __restrict__ AB, int nnodes)
{
    const int t  = threadIdx.x;
    const int wv = t >> 6;            // wave 0..3
    const int l  = t & 63;
    const int lr = l & 15;            // A-row-in-tile / B-col / D-col
    const int q  = l >> 4;            // 0..3
    const int n0 = blockIdx.x * 64 + wv * 16;
    const int arow = n0 + lr;
    const bool aval = (arow < nnodes);

    // ---- A fragments: h[arow][kt*32 + q*8 .. +8) truncated to bf16 ----
    bf16x8 ah[4];
    const float* hrow = h + (size_t)arow * 128;
#pragma unroll
    for (int kt = 0; kt < 4; ++kt) {
        float4 x0 = make_float4(0.f, 0.f, 0.f, 0.f);
        float4 x1 = make_float4(0.f, 0.f, 0.f, 0.f);
        if (aval) {
            x0 = *(const float4*)&hrow[kt * 32 + q * 8];
            x1 = *(const float4*)&hrow[kt * 32 + q * 8 + 4];
        }
        float xs[8] = {x0.x, x0.y, x0.z, x0.w, x1.x, x1.y, x1.z, x1.w};
        union { bf16x8 v; unsigned short u[8]; } H;
#pragma unroll
        for (int e = 0; e < 8; ++e)
            H.u[e] = (unsigned short)(__builtin_bit_cast(unsigned int, xs[e]) >> 16);
        ah[kt] = H.v;
    }

    const int drow = n0 + q * 4;      // D rows drow..drow+3, col = lr

#pragma unroll
    for (int jt = 0; jt < 8; ++jt) {
        f32x4 acc = {0.f, 0.f, 0.f, 0.f};
#pragma unroll
        for (int kt = 0; kt < 4; ++kt) {
            const int fb = ((jt * 4 + kt) * 64 + l) * 8;
            bf16x8 bh = *(const bf16x8*)(WPh + fb);
            bf16x8 bl = *(const bf16x8*)(WPl + fb);
            acc = __builtin_amdgcn_mfma_f32_16x16x32_bf16(ah[kt], bh, acc, 0, 0, 0);
            acc = __builtin_amdgcn_mfma_f32_16x16x32_bf16(ah[kt], bl, acc, 0, 0, 0);
        }
        const int j = jt * 16 + lr;
        const float bias = (jt < 4) ? b1[j] : 0.f;   // j<64 <=> jt<4 (compile-time)
#pragma unroll
        for (int r = 0; r < 4; ++r) {
            int n = drow + r;
            if (n < nnodes) AB[(size_t)n * 128 + j] = acc[r] + bias;
        }
    }
}

// ---------------------------------------------------------------------------
// Kernel 2: per-edge sample with fp32 boundary recompute.
// Fast path: hid = relu(AB[row][0:64] + AB[col][64:128]); logit = hid@W2+b2.
// If |logit+g1-g0| < 0.02 (~0.6% of edges), recompute logit in full fp32
// from h/W1/b1 -> decisions identical to the (passing) fp32 implementation.
// ---------------------------------------------------------------------------
__global__ __launch_bounds__(256)
void edge_sample(const float* __restrict__ AB, const float* __restrict__ h,
                 const float* __restrict__ W1, const float* __restrict__ b1,
                 const float* __restrict__ W2, const float* __restrict__ b2,
                 const float* __restrict__ u, const int* __restrict__ ei,
                 float* __restrict__ out)
{
    int t = threadIdx.x;
    int l = t & 15;
    int e = blockIdx.x * 16 + (t >> 4);

    int row = ei[e];
    int col = ei[NE + e];

    float4 a = *(const float4*)&AB[(size_t)row * 128 + l * 4];
    float4 b = *(const float4*)&AB[(size_t)col * 128 + 64 + l * 4];
    float4 w = *(const float4*)&W2[l * 4];

    float h0 = fmaxf(a.x + b.x, 0.f);
    float h1 = fmaxf(a.y + b.y, 0.f);
    float h2 = fmaxf(a.z + b.z, 0.f);
    float h3 = fmaxf(a.w + b.w, 0.f);

    float p = h0 * w.x + h1 * w.y + h2 * w.z + h3 * w.w;
    p += __shfl_xor(p, 1);
    p += __shfl_xor(p, 2);
    p += __shfl_xor(p, 4);
    p += __shfl_xor(p, 8);          // butterfly: every lane holds the sum

    float logit = p + b2[0];
    float g0 = 0.f, g1 = 0.f, dec = 0.f;
    if (l == 0) {
        float u0 = u[2 * e];
        float u1 = u[2 * e + 1];
        g0 = -logf(-logf(u0));
        g1 = -logf(-logf(u1));
        dec = (logit + g1) - g0;
    }
    int base = (t & 63) & ~15;      // group leader lane within wave
    float dec_b = __shfl(dec, base);

    if (fabsf(dec_b) < 0.02f) {
        // fp32 recompute: lane owns outputs 4l..4l+3
        float4 bb = *(const float4*)&b1[l * 4];
        float a0 = bb.x, a1 = bb.y, a2 = bb.z, a3 = bb.w;
        const float* hr = h + (size_t)row * 128;
        const float* hc = h + (size_t)col * 128;
        for (int k4 = 0; k4 < 32; ++k4) {
            float4 hv = *(const float4*)&hr[k4 * 4];
#pragma unroll
            for (int kk = 0; kk < 4; ++kk) {
                float4 wr = *(const float4*)&W1[(k4 * 4 + kk) * 64 + l * 4];
                float hval = (&hv.x)[kk];
                a0 += hval * wr.x; a1 += hval * wr.y;
                a2 += hval * wr.z; a3 += hval * wr.w;
            }
        }
        for (int k4 = 0; k4 < 32; ++k4) {
            float4 hv = *(const float4*)&hc[k4 * 4];
#pragma unroll
            for (int kk = 0; kk < 4; ++kk) {
                float4 wr = *(const float4*)&W1[(128 + k4 * 4 + kk) * 64 + l * 4];
                float hval = (&hv.x)[kk];
                a0 += hval * wr.x; a1 += hval * wr.y;
                a2 += hval * wr.z; a3 += hval * wr.w;
            }
        }
        float r0 = fmaxf(a0, 0.f), r1 = fmaxf(a1, 0.f);
        float r2 = fmaxf(a2, 0.f), r3 = fmaxf(a3, 0.f);
        float p2 = r0 * w.x + r1 * w.y + r2 * w.z + r3 * w.w;
        p2 += __shfl_xor(p2, 1);
        p2 += __shfl_xor(p2, 2);
        p2 += __shfl_xor(p2, 4);
        p2 += __shfl_xor(p2, 8);
        logit = p2 + b2[0];
    }

    if (l == 0) {
        out[e]      = (logit + g1 > g0) ? 1.0f : 0.0f;  // argmax tie -> 0
        out[NE + e] = logit;
    }
}

// ---------------------------------------------------------------------------
// Mid-tier fallback: R7 fp32 node_proj (ws holds AB but not the W pack).
// ---------------------------------------------------------------------------
__global__ __launch_bounds__(256)
void node_proj(const float* __restrict__ h, const float* __restrict__ W1,
               const float* __restrict__ b1, float* __restrict__ AB, int nnodes)
{
    __shared__ float lh[64 * 132];

    const int t   = threadIdx.x;
    const int tj  = t & 15;
    const int tnf = t >> 4;
    const int n0  = blockIdx.x * 64;

#pragma unroll
    for (int i = 0; i < 8; ++i) {
        int flat = i * 256 + t;
        int nl = flat >> 5;
        int c  = flat & 31;
        int ng = n0 + nl;
        float4 v = make_float4(0.f, 0.f, 0.f, 0.f);
        if (ng < nnodes) v = *(const float4*)&h[(size_t)ng * 128 + c * 4];
        *(float4*)&lh[nl * 132 + c * 4] = v;
    }
    __syncthreads();

    const float* wa_base = W1 + tj * 4;
    const float* wb_base = W1 + 128 * 64 + tj * 4;

    float acc[4][8];
    {
        float4 bv = *(const float4*)&b1[tj * 4];
#pragma unroll
        for (int r = 0; r < 4; ++r) {
            acc[r][0] = bv.x; acc[r][1] = bv.y; acc[r][2] = bv.z; acc[r][3] = bv.w;
            acc[r][4] = 0.f;  acc[r][5] = 0.f;  acc[r][6] = 0.f;  acc[r][7] = 0.f;
        }
    }

    float4 A0[4], B0[4], A1[4], B1[4];
#pragma unroll
    for (int kk = 0; kk < 4; ++kk) {
        A0[kk] = *(const float4*)&wa_base[kk * 64];
        B0[kk] = *(const float4*)&wb_base[kk * 64];
    }

#define LOAD_W(AX, BX, K4)                                              \
    _Pragma("unroll")                                                   \
    for (int kk = 0; kk < 4; ++kk) {                                    \
        AX[kk] = *(const float4*)&wa_base[((K4) * 4 + kk) * 64];        \
        BX[kk] = *(const float4*)&wb_base[((K4) * 4 + kk) * 64];        \
    }

#define COMPUTE(AX, BX, K4)                                             \
    {                                                                   \
        float4 hv[4];                                                   \
        _Pragma("unroll")                                               \
        for (int r = 0; r < 4; ++r)                                     \
            hv[r] = *(const float4*)&lh[(tnf + 16 * r) * 132 + (K4) * 4]; \
        _Pragma("unroll")                                               \
        for (int kk = 0; kk < 4; ++kk) {                                \
            float4 wa = AX[kk], wb = BX[kk];                            \
            _Pragma("unroll")                                           \
            for (int r = 0; r < 4; ++r) {                               \
                float hk = (kk == 0) ? hv[r].x : (kk == 1) ? hv[r].y    \
                         : (kk == 2) ? hv[r].z : hv[r].w;               \
                acc[r][0] += hk * wa.x;                                 \
                acc[r][1] += hk * wa.y;                                 \
                acc[r][2] += hk * wa.z;                                 \
                acc[r][3] += hk * wa.w;                                 \
                acc[r][4] += hk * wb.x;                                 \
                acc[r][5] += hk * wb.y;                                 \
                acc[r][6] += hk * wb.z;                                 \
                acc[r][7] += hk * wb.w;                                 \
            }                                                           \
        }                                                               \
    }

#pragma unroll 1
    for (int k4 = 0; k4 < 30; k4 += 2) {
        LOAD_W(A1, B1, k4 + 1)
        COMPUTE(A0, B0, k4)
        LOAD_W(A0, B0, k4 + 2)
        COMPUTE(A1, B1, k4 + 1)
    }
    LOAD_W(A1, B1, 31)
    COMPUTE(A0, B0, 30)
    COMPUTE(A1, B1, 31)

#undef LOAD_W
#undef COMPUTE

#pragma unroll
    for (int r = 0; r < 4; ++r) {
        int ng = n0 + tnf + 16 * r;
        if (ng >= nnodes) continue;
        float* orow = AB + (size_t)ng * 128;
        *(float4*)&orow[tj * 4]      = make_float4(acc[r][0], acc[r][1], acc[r][2], acc[r][3]);
        *(float4*)&orow[64 + tj * 4] = make_float4(acc[r][4], acc[r][5], acc[r][6], acc[r][7]);
    }
}

// ---------------------------------------------------------------------------
// Low-tier fallback: direct per-edge compute (no workspace).
// ---------------------------------------------------------------------------
__global__ __launch_bounds__(256)
void edge_direct(const float* __restrict__ h, const float* __restrict__ W1,
                 const float* __restrict__ b1, const float* __restrict__ W2,
                 const float* __restrict__ b2, const float* __restrict__ u,
                 const int* __restrict__ ei, float* __restrict__ out)
{
    int t = threadIdx.x;
    int l = t & 15;
    int e = blockIdx.x * 16 + (t >> 4);

    int row = ei[e];
    int col = ei[NE + e];

    float a0 = 0.f, a1 = 0.f, a2 = 0.f, a3 = 0.f;
    const float* hr = h + (size_t)row * 128;
    const float* hc = h + (size_t)col * 128;

    for (int k4 = 0; k4 < 32; ++k4) {
        float4 hv = *(const float4*)&hr[k4 * 4];
#pragma unroll
        for (int kk = 0; kk < 4; ++kk) {
            float4 wr = *(const float4*)&W1[(k4 * 4 + kk) * 64 + l * 4];
            float hval = (&hv.x)[kk];
            a0 += hval * wr.x; a1 += hval * wr.y; a2 += hval * wr.z; a3 += hval * wr.w;
        }
    }
    for (int k4 = 0; k4 < 32; ++k4) {
        float4 hv = *(const float4*)&hc[k4 * 4];
#pragma unroll
        for (int kk = 0; kk < 4; ++kk) {
            float4 wr = *(const float4*)&W1[(128 + k4 * 4 + kk) * 64 + l * 4];
            float hval = (&hv.x)[kk];
            a0 += hval * wr.x; a1 += hval * wr.y; a2 += hval * wr.z; a3 += hval * wr.w;
        }
    }
    float4 bb = *(const float4*)&b1[l * 4];
    float4 w  = *(const float4*)&W2[l * 4];
    float h0 = fmaxf(a0 + bb.x, 0.f);
    float h1 = fmaxf(a1 + bb.y, 0.f);
    float h2 = fmaxf(a2 + bb.z, 0.f);
    float h3 = fmaxf(a3 + bb.w, 0.f);

    float p = h0 * w.x + h1 * w.y + h2 * w.z + h3 * w.w;
    p += __shfl_xor(p, 1);
    p += __shfl_xor(p, 2);
    p += __shfl_xor(p, 4);
    p += __shfl_xor(p, 8);

    if (l == 0) {
        float logit = p + b2[0];
        float u0 = u[2 * e];
        float u1 = u[2 * e + 1];
        float g0 = -logf(-logf(u0));
        float g1 = -logf(-logf(u1));
        out[e]      = (logit + g1 > g0) ? 1.0f : 0.0f;
        out[NE + e] = logit;
    }
}

extern "C" void kernel_launch(void* const* d_in, const int* in_sizes, int n_in,
                              void* d_out, int out_size, void* d_ws, size_t ws_size,
                              hipStream_t stream)
{
    const float* h  = (const float*)d_in[0];
    const float* W1 = (const float*)d_in[1];
    const float* b1 = (const float*)d_in[2];
    const float* W2 = (const float*)d_in[3];
    const float* b2 = (const float*)d_in[4];
    const float* u  = (const float*)d_in[5];
    const int*   ei = (const int*)d_in[6];
    float* out = (float*)d_out;

    const size_t ab_bytes = (size_t)NN * 128 * sizeof(float);       // 51,200,000
    const size_t wp_bytes = 2u * 16384u * sizeof(unsigned short);   // 65,536
    float* AB = (float*)d_ws;

    if (ws_size >= ab_bytes + wp_bytes) {
        unsigned short* WPh = (unsigned short*)((char*)d_ws + ab_bytes);
        unsigned short* WPl = WPh + 16384;
        prepack_w<<<64, 256, 0, stream>>>(W1, WPh, WPl);
        mfma_proj<<<(NN + 63) / 64, 256, 0, stream>>>(h, WPh, WPl, b1, AB, NN);
        edge_sample<<<NE / 16, 256, 0, stream>>>(AB, h, W1, b1, W2, b2, u, ei, out);
    } else if (ws_size >= ab_bytes) {
        node_proj<<<(NN + 63) / 64, 256, 0, stream>>>(h, W1, b1, AB, NN);
        edge_sample<<<NE / 16, 256, 0, stream>>>(AB, h, W1, b1, W2, b2, u, ei, out);
    } else {
        edge_direct<<<NE / 16, 256, 0, stream>>>(h, W1, b1, W2, b2, u, ei, out);
    }
}